// Round 7
// baseline (1062.674 us; speedup 1.0000x reference)
//
#include <hip/hip_runtime.h>

constexpr int T = 1024;
constexpr int B = 64;
constexpr int V = 512;
constexpr int L = 256;
constexpr int S = 2 * L + 1;   // 513
constexpr int C = 16;          // scan chunk rows (128 B/lane, register-resident)

typedef float f32x4 __attribute__((ext_vector_type(4)));

__device__ __forceinline__ unsigned short f2bf(float f) {  // RNE
    unsigned u = __float_as_uint(f);
    u += 0x7fffu + ((u >> 16) & 1u);
    return (unsigned short)(u >> 16);
}

__device__ __forceinline__ float lane_bcast(float v, int i) {
    return __uint_as_float((unsigned)__builtin_amdgcn_readlane((int)__float_as_uint(v), i));
}
__device__ __forceinline__ int lane_bcast_i(int v, int i) {
    return __builtin_amdgcn_readlane(v, i);
}

// DPP lane shifts: pure VALU (no lgkm).
// WAVE_SHR1 (0x138): lane n <- lane n-1 (== __shfl_up by 1), lane 0 -> 0.
// WAVE_SHL1 (0x130): lane n <- lane n+1 (== __shfl_down by 1), lane 63 -> 0.
__device__ __forceinline__ float dpp_shr1z(float x) {
    return __uint_as_float((unsigned)__builtin_amdgcn_update_dpp(
        0, (int)__float_as_uint(x), 0x138, 0xf, 0xf, true));
}
__device__ __forceinline__ float dpp_shl1z(float x) {
    return __uint_as_float((unsigned)__builtin_amdgcn_update_dpp(
        0, (int)__float_as_uint(x), 0x130, 0xf, 0xf, true));
}
template <int CTRL, int RM>
__device__ __forceinline__ float dppmax(float m) {
    int mi = (int)__float_as_uint(m);
    int t = __builtin_amdgcn_update_dpp(mi, mi, CTRL, RM, 0xf, false);
    return fmaxf(m, __uint_as_float((unsigned)t));
}
template <int CTRL, int RM>
__device__ __forceinline__ float dppadd(float m) {
    int mi = (int)__float_as_uint(m);
    int t = __builtin_amdgcn_update_dpp(0, mi, CTRL, RM, 0xf, true);
    return m + __uint_as_float((unsigned)t);
}
#define DPPMAX_LADDER(m) do {                                                 \
        m = dppmax<0x111, 0xf>(m); m = dppmax<0x112, 0xf>(m);                 \
        m = dppmax<0x114, 0xf>(m); m = dppmax<0x118, 0xf>(m);                 \
        m = dppmax<0x142, 0xa>(m); m = dppmax<0x143, 0xc>(m);                 \
    } while (0)
#define DPPADD_LADDER(m) do {                                                 \
        m = dppadd<0x111, 0xf>(m); m = dppadd<0x112, 0xf>(m);                 \
        m = dppadd<0x114, 0xf>(m); m = dppadd<0x118, 0xf>(m);                 \
        m = dppadd<0x142, 0xa>(m); m = dppadd<0x143, 0xc>(m);                 \
    } while (0)

// ws layout (batch-major):
// [0]      lse_rows : B*T floats (256 KB)   [b*T+t]
// [256K]   blankU   : B*T floats (256 KB)   [b*T+t]  exp(blank logit)
// [512K]   cnt      : (T+1) ints — per-t completion flags (8 producers each)
//                     + cnt[T] = number of fully-done t's
// [768K]   logub    : B*T floats (256 KB)   [b*T+t]  blank LOGIT
// [1M]     packedR  : B*T*256 bf16 (32 MB)  exp(lab - blank) RATIOS
//
// R12 FUSION: setup and the serial scan ran back-to-back (~40 + ~32 us) while
// two fixed 512MiB harness re-poison fills (~154 us) dominate the budget. One
// kernel: blocks 0..63 = ctc (resident first, spin on per-t flags), blocks
// 64..8255 = setup producing t interleaved from BOTH ends so fwd(asc) and
// bwd(desc) scans are both fed immediately. Device-scope release/acquire
// per G16. lse/logub reduction runs on wave 2 gated by cnt[T].

__global__ __launch_bounds__(256) void fused_kernel(
    const float* __restrict__ acts, const int* __restrict__ labels,
    const int* __restrict__ act_lens, const int* __restrict__ label_lens,
    float* __restrict__ lse_rows, unsigned short* __restrict__ packedR,
    float* __restrict__ blankU, float* __restrict__ logub,
    int* __restrict__ cnt, float* __restrict__ out)
{
    __shared__ float rows[4][2][V];          // setup role: 16 KB
    __shared__ float sbr[S];                 // ctc role
    __shared__ float s_accb, s_sls, s_slog;

    const int lane = threadIdx.x & 63;
    const int wv   = threadIdx.x >> 6;

    // in-wave offsets prefix (lane l holds label_lens[l] and offsets[l])
    const int ll_l = label_lens[lane];
    int px = ll_l;
#pragma unroll
    for (int o = 1; o < 64; o <<= 1) {
        int y = __shfl_up(px, o, 64);
        if (lane >= o) px += y;
    }
    const int off_l = px - ll_l;

    if (blockIdx.x >= B) {
        // ================= SETUP ROLE =================
        const int k   = blockIdx.x - B;
        const int g   = k >> 3, sub = k & 7;
        const int t   = (g & 1) ? (T - 1 - (g >> 1)) : (g >> 1);
        const int rbase = t * B + sub * 8 + wv * 2;     // rows rbase, rbase+1
        const f32x4* p = (const f32x4*)(acts + (size_t)rbase * V);

        f32x4 xa0 = __builtin_nontemporal_load(p + lane);
        f32x4 xa1 = __builtin_nontemporal_load(p + lane + 64);
        f32x4 xb0 = __builtin_nontemporal_load(p + lane + 128);
        f32x4 xb1 = __builtin_nontemporal_load(p + lane + 192);
        f32x4 ea0, ea1, eb0, eb1;
        ea0.x=__expf(xa0.x); ea0.y=__expf(xa0.y); ea0.z=__expf(xa0.z); ea0.w=__expf(xa0.w);
        ea1.x=__expf(xa1.x); ea1.y=__expf(xa1.y); ea1.z=__expf(xa1.z); ea1.w=__expf(xa1.w);
        eb0.x=__expf(xb0.x); eb0.y=__expf(xb0.y); eb0.z=__expf(xb0.z); eb0.w=__expf(xb0.w);
        eb1.x=__expf(xb1.x); eb1.y=__expf(xb1.y); eb1.z=__expf(xb1.z); eb1.w=__expf(xb1.w);
        ((f32x4*)rows[wv][0])[lane]      = ea0;
        ((f32x4*)rows[wv][0])[lane + 64] = ea1;
        ((f32x4*)rows[wv][1])[lane]      = eb0;
        ((f32x4*)rows[wv][1])[lane + 64] = eb1;
        float sa = ea0.x+ea0.y+ea0.z+ea0.w + ea1.x+ea1.y+ea1.z+ea1.w;
        float sb = eb0.x+eb0.y+eb0.z+eb0.w + eb1.x+eb1.y+eb1.z+eb1.w;
        DPPADD_LADDER(sa); DPPADD_LADDER(sb);
        sa = lane_bcast(sa, 63); sb = lane_bcast(sb, 63);

        const float xblk0 = lane_bcast(xa0.x, 0);
        const float xblk1 = lane_bcast(xb0.x, 0);

#pragma unroll
        for (int rr = 0; rr < 2; ++rr) {
            const int r = rbase + rr;
            const int b = r & (B - 1);
            const float* rw = rows[wv][rr];
            const int lab_len = lane_bcast_i(ll_l, b);
            const int off     = lane_bcast_i(off_l, b);
            const float ubk   = rw[0];
            const float rub   = __builtin_amdgcn_rcpf(ubk);
            const int j0 = 4 * lane;
            float q0 = (j0 + 0 < lab_len) ? rw[labels[min(off + j0 + 0, B * L - 1)]] * rub : 1.f;
            float q1 = (j0 + 1 < lab_len) ? rw[labels[min(off + j0 + 1, B * L - 1)]] * rub : 1.f;
            float q2 = (j0 + 2 < lab_len) ? rw[labels[min(off + j0 + 2, B * L - 1)]] * rub : 1.f;
            float q3 = (j0 + 3 < lab_len) ? rw[labels[min(off + j0 + 3, B * L - 1)]] * rub : 1.f;
            ushort4 hv = {f2bf(q0), f2bf(q1), f2bf(q2), f2bf(q3)};
            ((ushort4*)packedR)[(size_t)(b * T + t) * 64 + lane] = hv;
            if (lane == 0) {
                lse_rows[b * T + t] = __logf(rr ? sb : sa);
                blankU[b * T + t]   = ubk;
                logub[b * T + t]    = rr ? xblk1 : xblk0;
            }
        }
        __syncthreads();
        if (threadIdx.x == 0) {
            __threadfence();
            int old = __hip_atomic_fetch_add(&cnt[t], 1, __ATOMIC_RELEASE,
                                             __HIP_MEMORY_SCOPE_AGENT);
            if (old == 7)
                __hip_atomic_fetch_add(&cnt[T], 1, __ATOMIC_RELEASE,
                                       __HIP_MEMORY_SCOPE_AGENT);
        }
        return;
    }

    // ================= CTC ROLE =================
    const int b       = blockIdx.x;
    const int lab_len = lane_bcast_i(ll_l, b);
    const int a_len   = act_lens[b];
    const int th      = (a_len - 1) >> 1;
    const int thp1    = th + 1;
    const int off     = lane_bcast_i(off_l, b);
    const size_t rowbase = (size_t)b * T;

    int li0 = 4 * lane;
    int eprev = (li0 - 1 >= 0 && li0 - 1 < lab_len) ? labels[min(off + li0 - 1, B * L - 1)] : 0;
    int enext = (li0 + 4 < lab_len) ? labels[min(off + li0 + 4, B * L - 1)] : 0;
    int e0 = (li0 + 0 < lab_len) ? labels[min(off + li0 + 0, B * L - 1)] : 0;
    int e1 = (li0 + 1 < lab_len) ? labels[min(off + li0 + 1, B * L - 1)] : 0;
    int e2 = (li0 + 2 < lab_len) ? labels[min(off + li0 + 2, B * L - 1)] : 0;
    int e3 = (li0 + 3 < lab_len) ? labels[min(off + li0 + 3, B * L - 1)] : 0;

    const float aF0 = (8 * lane + 1 >= 2 && e0 != 0 && e0 != eprev) ? 1.f : 0.f;
    const float aF1 = (e1 != 0 && e1 != e0) ? 1.f : 0.f;
    const float aF2 = (e2 != 0 && e2 != e1) ? 1.f : 0.f;
    const float aF3 = (e3 != 0 && e3 != e2) ? 1.f : 0.f;
    const float aB0 = aF1, aB1 = aF2, aB2 = aF3;
    const float aB3 = (enext != 0 && enext != e3) ? 1.f : 0.f;

    float A0 = 0.f, A1 = 0.f, A2 = 0.f, A3 = 0.f, A4 = 0.f,
          A5 = 0.f, A6 = 0.f, A7 = 0.f, A8 = 0.f;
    float acc = 0.f;

    uint2 a_0,a_1,a_2,a_3,a_4,a_5,a_6,a_7,a_8,a_9,a_10,a_11,a_12,a_13,a_14,a_15;
    uint2 b_0,b_1,b_2,b_3,b_4,b_5,b_6,b_7,b_8,b_9,b_10,b_11,b_12,b_13,b_14,b_15;
    uint2 c_0,c_1,c_2,c_3,c_4,c_5,c_6,c_7,c_8,c_9,c_10,c_11,c_12,c_13,c_14,c_15;

#define PINV(x) asm volatile("" : "+v"(x))
#define APPLY16(M, P) M(P,0) M(P,1) M(P,2) M(P,3) M(P,4) M(P,5) M(P,6) M(P,7) \
                      M(P,8) M(P,9) M(P,10) M(P,11) M(P,12) M(P,13) M(P,14) M(P,15)

#define WAIT1(TT) do {                                                        \
        if (lane == 0) {                                                      \
            while (__hip_atomic_load(&cnt[(TT)], __ATOMIC_RELAXED,            \
                                     __HIP_MEMORY_SCOPE_AGENT) != 8)          \
                __builtin_amdgcn_s_sleep(8);                                  \
        }                                                                     \
        __hip_atomic_load(&cnt[(TT)], __ATOMIC_ACQUIRE,                       \
                          __HIP_MEMORY_SCOPE_AGENT);                          \
    } while (0)

#define WAITWIN(TLO) do {                                                     \
        const int tw_ = min(max((int)(TLO), 0), T - C);                       \
        if (lane < C) {                                                       \
            while (__hip_atomic_load(&cnt[tw_ + lane], __ATOMIC_RELAXED,      \
                                     __HIP_MEMORY_SCOPE_AGENT) != 8)          \
                __builtin_amdgcn_s_sleep(8);                                  \
        }                                                                     \
        __hip_atomic_load(&cnt[tw_], __ATOMIC_ACQUIRE,                        \
                          __HIP_MEMORY_SCOPE_AGENT);                          \
    } while (0)

#define LD1(P, I) P##_##I = gp_[(I) * 64 + lane];
#define LOADCH(P, TLO) do {                                                   \
        const int tl_ = min(max((int)(TLO), 0), T - C);                       \
        const uint2* gp_ = (const uint2*)(packedR + (rowbase + tl_) * 256);   \
        APPLY16(LD1, P)                                                       \
    } while (0)

#define PIN1(P, I) PINV(P##_##I.x); PINV(P##_##I.y);
#define PINCH(P) do { APPLY16(PIN1, P) } while (0)

#define RESCALE() do {                                                        \
        float m_ = fmaxf(A8, A0); m_ = fmaxf(m_, A1); m_ = fmaxf(m_, A2);     \
        m_ = fmaxf(m_, A3); m_ = fmaxf(m_, A4); m_ = fmaxf(m_, A5);           \
        m_ = fmaxf(m_, A6); m_ = fmaxf(m_, A7);                               \
        DPPMAX_LADDER(m_);                                                    \
        m_ = lane_bcast(m_, 63);                                              \
        m_ = fmaxf(m_, 1e-30f);                                               \
        float inv_ = __builtin_amdgcn_rcpf(m_);                               \
        acc += __logf(m_);                                                    \
        A0 *= inv_; A1 *= inv_; A2 *= inv_; A3 *= inv_; A4 *= inv_;           \
        A5 *= inv_; A6 *= inv_; A7 *= inv_; A8 *= inv_;                       \
    } while (0)

#define STEPF_CORE(HX, HY) do {                                               \
        const unsigned hx_ = (HX), hy_ = (HY);                                \
        const float u0_ = __uint_as_float(hx_ << 16);                         \
        const float u1_ = __uint_as_float(hx_ & 0xffff0000u);                 \
        const float u2_ = __uint_as_float(hy_ << 16);                         \
        const float u3_ = __uint_as_float(hy_ & 0xffff0000u);                 \
        const float pA7_ = dpp_shr1z(A7);                                     \
        A8 = A8 + A7;                                                         \
        A7 = u3_ * fmaf(aF3, A5, A7 + A6);                                    \
        A6 = A6 + A5;                                                         \
        A5 = u2_ * fmaf(aF2, A3, A5 + A4);                                    \
        A4 = A4 + A3;                                                         \
        A3 = u1_ * fmaf(aF1, A1, A3 + A2);                                    \
        A2 = A2 + A1;                                                         \
        A1 = u0_ * fmaf(aF0, pA7_, A1 + A0);                                  \
        A0 = A0 + pA7_;                                                       \
    } while (0)

#define STEPB_CORE(HX, HY) do {                                               \
        const unsigned hx_ = (HX), hy_ = (HY);                                \
        const float u0_ = __uint_as_float(hx_ << 16);                         \
        const float u1_ = __uint_as_float(hx_ & 0xffff0000u);                 \
        const float u2_ = __uint_as_float(hy_ << 16);                         \
        const float u3_ = __uint_as_float(hy_ & 0xffff0000u);                 \
        const float nC0_ = dpp_shl1z(A0);                                     \
        A8 = A8 + A0;                                                         \
        A0 = u0_ * fmaf(aB0, A2, A0 + A1);                                    \
        A1 = A1 + A2;                                                         \
        A2 = u1_ * fmaf(aB1, A4, A2 + A3);                                    \
        A3 = A3 + A4;                                                         \
        A4 = u2_ * fmaf(aB2, A6, A4 + A5);                                    \
        A5 = A5 + A6;                                                         \
        A6 = u3_ * fmaf(aB3, nC0_, A6 + A7);                                  \
        A7 = A7 + nC0_;                                                       \
    } while (0)

#define SF(P, I)  STEPF_CORE(P##_##I.x, P##_##I.y);
#define SB(P, I)  STEPB_CORE(P##_##I.x, P##_##I.y);
#define SFG(P, I, TLO) if ((TLO) + (I) <= th)   { SF(P, I) }
#define SBG(P, I, TLO) if ((TLO) + (I) >= thp1) { SB(P, I) }

#define DOF16(P) do {                                                         \
        SF(P,0) SF(P,1) SF(P,2) SF(P,3) SF(P,4) SF(P,5) SF(P,6) SF(P,7)       \
        RESCALE();                                                            \
        SF(P,8) SF(P,9) SF(P,10) SF(P,11) SF(P,12) SF(P,13) SF(P,14) SF(P,15) \
        RESCALE();                                                            \
    } while (0)
#define DOFPART(P, TLO) do {                                                  \
        SFG(P,0,TLO) SFG(P,1,TLO) SFG(P,2,TLO) SFG(P,3,TLO)                   \
        SFG(P,4,TLO) SFG(P,5,TLO) SFG(P,6,TLO) SFG(P,7,TLO)                   \
        RESCALE();                                                            \
        SFG(P,8,TLO) SFG(P,9,TLO) SFG(P,10,TLO) SFG(P,11,TLO)                 \
        SFG(P,12,TLO) SFG(P,13,TLO) SFG(P,14,TLO) SFG(P,15,TLO)               \
        RESCALE();                                                            \
    } while (0)
#define DOB16(P) do {                                                         \
        SB(P,15) SB(P,14) SB(P,13) SB(P,12) SB(P,11) SB(P,10) SB(P,9) SB(P,8) \
        RESCALE();                                                            \
        SB(P,7) SB(P,6) SB(P,5) SB(P,4) SB(P,3) SB(P,2) SB(P,1) SB(P,0)       \
        RESCALE();                                                            \
    } while (0)
#define DOBPART(P, TLO) do {                                                  \
        SBG(P,15,TLO) SBG(P,14,TLO) SBG(P,13,TLO) SBG(P,12,TLO)               \
        SBG(P,11,TLO) SBG(P,10,TLO) SBG(P,9,TLO) SBG(P,8,TLO)                 \
        RESCALE();                                                            \
        SBG(P,7,TLO) SBG(P,6,TLO) SBG(P,5,TLO) SBG(P,4,TLO)                   \
        SBG(P,3,TLO) SBG(P,2,TLO) SBG(P,1,TLO) SBG(P,0,TLO)                   \
        RESCALE();                                                            \
    } while (0)

#define STEP_DIRECT(WHICH, TT) do {                                           \
        uint2 hvd_ = ((const uint2*)(packedR + (rowbase + (TT)) * 256))[lane];\
        WHICH(hvd_.x, hvd_.y);                                                \
    } while (0)

#define PREFF(P, CI) do { if ((CI) < nc) { WAITWIN(1 + C * (CI));             \
        LOADCH(P, 1 + C * (CI)); } } while (0)
#define PREFB(P, CI) do { if ((CI) < nc) { WAITWIN(a_len - 17 - C * (CI));    \
        LOADCH(P, a_len - 17 - C * (CI)); } } while (0)

    if (wv == 0) {
        // ---------- forward scan ----------
        WAIT1(0);
        if (lane == 0) {
            A0 = blankU[rowbase];
            A1 = __uint_as_float(((unsigned)packedR[rowbase * 256]) << 16) * A0;
        }
        if (th >= 1) {
            const int nc    = (th + C - 1) / C;
            const int nfull = th / C;
            PREFF(a, 0); PREFF(b, 1); PREFF(c, 2);
            int cc = 0;
            for (; cc + 3 <= nfull; cc += 3) {
                PINCH(a); DOF16(a); PREFF(a, cc + 3);
                PINCH(b); DOF16(b); PREFF(b, cc + 4);
                PINCH(c); DOF16(c); PREFF(c, cc + 5);
            }
            const int rem = nfull - cc;
            if (rem == 0) {
                if (nc > nfull) { PINCH(a); DOFPART(a, 1 + C * cc); }
            } else if (rem == 1) {
                PINCH(a); DOF16(a);
                if (nc > nfull) { PINCH(b); DOFPART(b, 1 + C * (cc + 1)); }
            } else {
                PINCH(a); DOF16(a);
                PINCH(b); DOF16(b);
                if (nc > nfull) { PINCH(c); DOFPART(c, 1 + C * (cc + 2)); }
            }
        }
    } else if (wv == 1) {
        // ---------- backward scan ----------
        WAIT1(a_len - 1);
        const int send = 2 * lab_len;
        {
            size_t rl = rowbase + (a_len - 1);
            float ubl = blankU[rl];
            float ue  = (lab_len > 0)
                      ? __uint_as_float(((unsigned)packedR[rl * 256 + (lab_len - 1)]) << 16) * ubl
                      : 0.f;
            int s0 = 8 * lane + 1;
            A0 = (s0 + 0 == send) ? ubl : ((s0 + 0 == send - 1) ? ue : 0.f);
            A1 = (s0 + 1 == send) ? ubl : ((s0 + 1 == send - 1) ? ue : 0.f);
            A2 = (s0 + 2 == send) ? ubl : ((s0 + 2 == send - 1) ? ue : 0.f);
            A3 = (s0 + 3 == send) ? ubl : ((s0 + 3 == send - 1) ? ue : 0.f);
            A4 = (s0 + 4 == send) ? ubl : ((s0 + 4 == send - 1) ? ue : 0.f);
            A5 = (s0 + 5 == send) ? ubl : ((s0 + 5 == send - 1) ? ue : 0.f);
            A6 = (s0 + 6 == send) ? ubl : ((s0 + 6 == send - 1) ? ue : 0.f);
            A7 = (s0 + 7 == send) ? ubl : ((s0 + 7 == send - 1) ? ue : 0.f);
            A8 = (send == 0) ? ubl : 0.f;
        }

        const int nstB = a_len - 2 - th;
        if (nstB > 0 && a_len >= 17) {
            const int nc    = (nstB + C - 1) / C;
            const int nfull = nstB / C;
            PREFB(a, 0); PREFB(b, 1); PREFB(c, 2);
            int cc = 0;
            for (; cc + 3 <= nfull; cc += 3) {
                PINCH(a); DOB16(a); PREFB(a, cc + 3);
                PINCH(b); DOB16(b); PREFB(b, cc + 4);
                PINCH(c); DOB16(c); PREFB(c, cc + 5);
            }
            const int rem = nfull - cc;
            if (rem == 0) {
                if (nc > nfull) { PINCH(a); DOBPART(a, a_len - 17 - C * cc); }
            } else if (rem == 1) {
                PINCH(a); DOB16(a);
                if (nc > nfull) { PINCH(b); DOBPART(b, a_len - 17 - C * (cc + 1)); }
            } else {
                PINCH(a); DOB16(a);
                PINCH(b); DOB16(b);
                if (nc > nfull) { PINCH(c); DOBPART(c, a_len - 17 - C * (cc + 2)); }
            }
        } else if (nstB > 0) {                      // tiny a_len fallback
            WAITWIN(0);                             // covers t 0..15 (a_len<17)
            for (int t = a_len - 2; t >= thp1; --t) {
                STEP_DIRECT(STEPB_CORE, t);
                if (((a_len - 2 - t) & 7) == 7) RESCALE();
            }
        }

        {   // bracket W(s) = B(s) + B(s+1) + allow(s+2)*B(s+2)
            float nC0 = dpp_shl1z(A0);
            float w1 = fmaf(aB0, A2, A0 + A1);
            float w2 = A1 + A2;
            float w3 = fmaf(aB1, A4, A2 + A3);
            float w4 = A3 + A4;
            float w5 = fmaf(aB2, A6, A4 + A5);
            float w6 = A5 + A6;
            float w7 = fmaf(aB3, nC0, A6 + A7);
            float w8 = A7 + nC0;
            int sB = 8 * lane + 1;
            sbr[sB + 0] = w1; sbr[sB + 1] = w2; sbr[sB + 2] = w3; sbr[sB + 3] = w4;
            sbr[sB + 4] = w5; sbr[sB + 5] = w6; sbr[sB + 6] = w7; sbr[sB + 7] = w8;
            if (lane == 0) sbr[0] = A8 + A0;
            if (lane == 0) s_accb = acc;
        }
    } else if (wv == 2) {
        // ---------- lse + interior-logub reduction (after all t done) ----------
        if (lane == 0) {
            while (__hip_atomic_load(&cnt[T], __ATOMIC_RELAXED,
                                     __HIP_MEMORY_SCOPE_AGENT) != T)
                __builtin_amdgcn_s_sleep(16);
        }
        __hip_atomic_load(&cnt[T], __ATOMIC_ACQUIRE, __HIP_MEMORY_SCOPE_AGENT);
        float s = 0.f, g = 0.f;
        if (a_len == T) {
            const f32x4* lp = (const f32x4*)(lse_rows + rowbase);
            const f32x4* gp = (const f32x4*)(logub + rowbase);
            f32x4 s0 = lp[lane], s1 = lp[lane + 64],
                  s2 = lp[lane + 128], s3 = lp[lane + 192];
            f32x4 g0 = gp[lane], g1 = gp[lane + 64],
                  g2 = gp[lane + 128], g3 = gp[lane + 192];
            s = s0.x+s0.y+s0.z+s0.w + s1.x+s1.y+s1.z+s1.w
              + s2.x+s2.y+s2.z+s2.w + s3.x+s3.y+s3.z+s3.w;
            g = g0.x+g0.y+g0.z+g0.w + g1.x+g1.y+g1.z+g1.w
              + g2.x+g2.y+g2.z+g2.w + g3.x+g3.y+g3.z+g3.w;
            DPPADD_LADDER(s); DPPADD_LADDER(g);
            s = lane_bcast(s, 63);
            g = lane_bcast(g, 63) - logub[rowbase] - logub[rowbase + T - 1];
        } else {
            for (int t = lane; t < a_len; t += 64) {
                s += lse_rows[rowbase + t];
                if (t >= 1 && t <= a_len - 2) g += logub[rowbase + t];
            }
            DPPADD_LADDER(s); DPPADD_LADDER(g);
            s = lane_bcast(s, 63); g = lane_bcast(g, 63);
        }
        if (lane == 0) { s_sls = s; s_slog = g; }
    }
    __syncthreads();
    if (wv == 0) {
        // LOG-space junction
        const float sls = s_sls, slog = s_slog;
        int s0 = 8 * lane;
        float p0 = __logf(fmaxf(A0, 1e-37f)) + __logf(fmaxf(sbr[s0 + 0], 1e-37f));
        float p1 = __logf(fmaxf(A1, 1e-37f)) + __logf(fmaxf(sbr[s0 + 1], 1e-37f));
        float p2 = __logf(fmaxf(A2, 1e-37f)) + __logf(fmaxf(sbr[s0 + 2], 1e-37f));
        float p3 = __logf(fmaxf(A3, 1e-37f)) + __logf(fmaxf(sbr[s0 + 3], 1e-37f));
        float p4 = __logf(fmaxf(A4, 1e-37f)) + __logf(fmaxf(sbr[s0 + 4], 1e-37f));
        float p5 = __logf(fmaxf(A5, 1e-37f)) + __logf(fmaxf(sbr[s0 + 5], 1e-37f));
        float p6 = __logf(fmaxf(A6, 1e-37f)) + __logf(fmaxf(sbr[s0 + 6], 1e-37f));
        float p7 = __logf(fmaxf(A7, 1e-37f)) + __logf(fmaxf(sbr[s0 + 7], 1e-37f));
        float p8 = -3.0e38f;
        if (lane == 63) p8 = __logf(fmaxf(A8, 1e-37f)) + __logf(fmaxf(sbr[512], 1e-37f));
        float pmax = fmaxf(fmaxf(fmaxf(p0, p1), fmaxf(p2, p3)),
                           fmaxf(fmaxf(p4, p5), fmaxf(p6, p7)));
        pmax = fmaxf(pmax, p8);
        DPPMAX_LADDER(pmax);
        pmax = lane_bcast(pmax, 63);
        float dot = __expf(p0 - pmax) + __expf(p1 - pmax) + __expf(p2 - pmax)
                  + __expf(p3 - pmax) + __expf(p4 - pmax) + __expf(p5 - pmax)
                  + __expf(p6 - pmax) + __expf(p7 - pmax);
        if (lane == 63) dot += __expf(p8 - pmax);
        DPPADD_LADDER(dot);
        dot = lane_bcast(dot, 63);
        if (lane == 0) {
            float loss = sls - slog - acc - s_accb - (pmax + __logf(dot));
            atomicAdd(out, loss);
        }
    }
#undef PINV
#undef APPLY16
#undef WAIT1
#undef WAITWIN
#undef LD1
#undef LOADCH
#undef PIN1
#undef PINCH
#undef RESCALE
#undef STEPF_CORE
#undef STEPB_CORE
#undef SF
#undef SB
#undef SFG
#undef SBG
#undef DOF16
#undef DOFPART
#undef DOB16
#undef DOBPART
#undef STEP_DIRECT
#undef PREFF
#undef PREFB
}

extern "C" void kernel_launch(void* const* d_in, const int* in_sizes, int n_in,
                              void* d_out, int out_size, void* d_ws, size_t ws_size,
                              hipStream_t stream) {
    const float* acts       = (const float*)d_in[0];
    const int*   labels     = (const int*)d_in[1];
    const int*   act_lens   = (const int*)d_in[2];
    const int*   label_lens = (const int*)d_in[3];
    float*       out        = (float*)d_out;

    float*          lse_rows = (float*)d_ws;
    float*          blankU   = (float*)((char*)d_ws + (size_t)T * B * 4);
    int*            cnt      = (int*)  ((char*)d_ws + (size_t)2 * T * B * 4);
    float*          logub    = (float*)((char*)d_ws + (size_t)3 * T * B * 4);
    unsigned short* packedR  = (unsigned short*)((char*)d_ws + (1u << 20));

    hipMemsetAsync(d_out, 0, sizeof(float), stream);
    hipMemsetAsync(cnt, 0, (T + 1) * sizeof(int), stream);

    fused_kernel<<<B + T * B / 8, 256, 0, stream>>>(
        acts, labels, act_lens, label_lens,
        lse_rows, packedR, blankU, logub, cnt, out);
}

// Round 8
// 291.154 us; speedup vs baseline: 3.6499x; 3.6499x over previous
//
#include <hip/hip_runtime.h>

constexpr int T = 1024;
constexpr int B = 64;
constexpr int V = 512;
constexpr int L = 256;
constexpr int S = 2 * L + 1;   // 513
constexpr int RING = 48;       // ring rows per direction (3 chunks of 16)

typedef float f32x4 __attribute__((ext_vector_type(4)));

__device__ __forceinline__ unsigned short f2bf(float f) {  // RNE
    unsigned u = __float_as_uint(f);
    u += 0x7fffu + ((u >> 16) & 1u);
    return (unsigned short)(u >> 16);
}

__device__ __forceinline__ float lane_bcast(float v, int i) {
    return __uint_as_float((unsigned)__builtin_amdgcn_readlane((int)__float_as_uint(v), i));
}
__device__ __forceinline__ int lane_bcast_i(int v, int i) {
    return __builtin_amdgcn_readlane(v, i);
}
__device__ __forceinline__ float sel4(f32x4 a, int s) {
    return s == 0 ? a.x : s == 1 ? a.y : s == 2 ? a.z : a.w;
}

// DPP lane shifts: pure VALU (no lgkm).
__device__ __forceinline__ float dpp_shr1z(float x) {   // lane n <- n-1, lane0 -> 0
    return __uint_as_float((unsigned)__builtin_amdgcn_update_dpp(
        0, (int)__float_as_uint(x), 0x138, 0xf, 0xf, true));
}
__device__ __forceinline__ float dpp_shl1z(float x) {   // lane n <- n+1, lane63 -> 0
    return __uint_as_float((unsigned)__builtin_amdgcn_update_dpp(
        0, (int)__float_as_uint(x), 0x130, 0xf, 0xf, true));
}
template <int CTRL, int RM>
__device__ __forceinline__ float dppmax(float m) {
    int mi = (int)__float_as_uint(m);
    int t = __builtin_amdgcn_update_dpp(mi, mi, CTRL, RM, 0xf, false);
    return fmaxf(m, __uint_as_float((unsigned)t));
}
template <int CTRL, int RM>
__device__ __forceinline__ float dppadd(float m) {
    int mi = (int)__float_as_uint(m);
    int t = __builtin_amdgcn_update_dpp(0, mi, CTRL, RM, 0xf, true);
    return m + __uint_as_float((unsigned)t);
}
#define DPPMAX_LADDER(m) do {                                                 \
        m = dppmax<0x111, 0xf>(m); m = dppmax<0x112, 0xf>(m);                 \
        m = dppmax<0x114, 0xf>(m); m = dppmax<0x118, 0xf>(m);                 \
        m = dppmax<0x142, 0xa>(m); m = dppmax<0x143, 0xc>(m);                 \
    } while (0)
#define DPPADD_LADDER(m) do {                                                 \
        m = dppadd<0x111, 0xf>(m); m = dppadd<0x112, 0xf>(m);                 \
        m = dppadd<0x114, 0xf>(m); m = dppadd<0x118, 0xf>(m);                 \
        m = dppadd<0x142, 0xa>(m); m = dppadd<0x143, 0xc>(m);                 \
    } while (0)

// ---------------------------------------------------------------------------
// R13: single-workgroup producer/consumer CTC. R7's cross-block fusion died on
// agent-scope coherence (every release = L2 writeback, every acquire = L2
// invalidate -> 938us storm). Here the pipeline lives INSIDE one block:
// w0=fwd scan, w1=bwd scan, w2-4=fwd producers, w5-7=bwd producers. Producers
// stream acts rows 4-deep, exp+gather+pack bf16 RATIOS (R11 form) into two
// 48-row LDS rings; sync is workgroup-scope LDS atomics (pure ds ops, no
// cache maintenance). No workspace, no setup kernel, no 32MB packedR.
// sched_barrier(0) after every load batch pins issue points (the compiler
// otherwise sinks "prefetch" loads to their use - R3-R6's hidden stall).
// ---------------------------------------------------------------------------
__global__ __launch_bounds__(512, 1) void fused_kernel(
    const float* __restrict__ acts, const int* __restrict__ labels,
    const int* __restrict__ act_lens, const int* __restrict__ label_lens,
    float* __restrict__ out)
{
    __shared__ unsigned short ringF[RING * 256];   // 24 KB
    __shared__ unsigned short ringB[RING * 256];   // 24 KB
    __shared__ float stage[6][V];                  // 12 KB (per-producer scratch)
    __shared__ float sbr[S];                       // 2052 B
    __shared__ int   readyF[3], readyB[3], consF, consB;
    __shared__ float parts_sls[8], parts_slog[8], s_accb;

    const int lane = threadIdx.x & 63;
    const int wv   = threadIdx.x >> 6;
    const int b    = blockIdx.x;

    if (threadIdx.x == 0) {
        readyF[0] = -3; readyF[1] = -2; readyF[2] = -1;
        readyB[0] = -3; readyB[1] = -2; readyB[2] = -1;
        consF = -1; consB = -1;
    }

    const int a_len = act_lens[b];
    const int th    = (a_len - 1) >> 1;
    const int NF    = th;                                   // fwd steps, t = 1+s
    const int nbr   = a_len - 2 - th;
    const int NB    = nbr > 0 ? nbr : 0;                    // bwd steps, t = a_len-2-s

    // in-wave offsets prefix (lane l holds label_lens[l], offsets[l])
    const int ll_l = label_lens[lane];
    int px = ll_l;
#pragma unroll
    for (int o = 1; o < 64; o <<= 1) {
        int y = __shfl_up(px, o, 64);
        if (lane >= o) px += y;
    }
    const int off_l   = px - ll_l;
    const int lab_len = lane_bcast_i(ll_l, b);
    const int off     = lane_bcast_i(off_l, b);

    const int li0 = 4 * lane;
    int eprev = (li0 - 1 >= 0 && li0 - 1 < lab_len) ? labels[min(off + li0 - 1, B * L - 1)] : 0;
    int enext = (li0 + 4 < lab_len) ? labels[min(off + li0 + 4, B * L - 1)] : 0;
    int e0 = (li0 + 0 < lab_len) ? labels[min(off + li0 + 0, B * L - 1)] : 0;
    int e1 = (li0 + 1 < lab_len) ? labels[min(off + li0 + 1, B * L - 1)] : 0;
    int e2 = (li0 + 2 < lab_len) ? labels[min(off + li0 + 2, B * L - 1)] : 0;
    int e3 = (li0 + 3 < lab_len) ? labels[min(off + li0 + 3, B * L - 1)] : 0;

    const float aF0 = (8 * lane + 1 >= 2 && e0 != 0 && e0 != eprev) ? 1.f : 0.f;
    const float aF1 = (e1 != 0 && e1 != e0) ? 1.f : 0.f;
    const float aF2 = (e2 != 0 && e2 != e1) ? 1.f : 0.f;
    const float aF3 = (e3 != 0 && e3 != e2) ? 1.f : 0.f;
    const float aB0 = aF1, aB1 = aF2, aB2 = aF3;
    const float aB3 = (enext != 0 && enext != e3) ? 1.f : 0.f;

    float A0 = 0.f, A1 = 0.f, A2 = 0.f, A3 = 0.f, A4 = 0.f,
          A5 = 0.f, A6 = 0.f, A7 = 0.f, A8 = 0.f;
    float acc = 0.f;

    uint2 a_0,a_1,a_2,a_3,a_4,a_5,a_6,a_7,a_8,a_9,a_10,a_11,a_12,a_13,a_14,a_15;
    uint2 b_0,b_1,b_2,b_3,b_4,b_5,b_6,b_7,b_8,b_9,b_10,b_11,b_12,b_13,b_14,b_15;
    uint2 c_0,c_1,c_2,c_3,c_4,c_5,c_6,c_7,c_8,c_9,c_10,c_11,c_12,c_13,c_14,c_15;

    __syncthreads();   // counters visible to all waves

#define PINV(x) asm volatile("" : "+v"(x))
#define APPLY16(M, P) M(P,0) M(P,1) M(P,2) M(P,3) M(P,4) M(P,5) M(P,6) M(P,7) \
                      M(P,8) M(P,9) M(P,10) M(P,11) M(P,12) M(P,13) M(P,14) M(P,15)
#define APPLY16B(M, P, X) M(P,0,X) M(P,1,X) M(P,2,X) M(P,3,X) M(P,4,X) M(P,5,X) \
                          M(P,6,X) M(P,7,X) M(P,8,X) M(P,9,X) M(P,10,X) M(P,11,X) \
                          M(P,12,X) M(P,13,X) M(P,14,X) M(P,15,X)
#define PIN1(P, I) PINV(P##_##I.x); PINV(P##_##I.y);
#define PINCH(P) do { APPLY16(PIN1, P) } while (0)

#define LDF1(P, I, BB) P##_##I = *(const uint2*)((const char*)ringF + (BB) + (I) * 512 + lane * 8);
#define LDB1(P, I, BB) P##_##I = *(const uint2*)((const char*)ringB + (BB) + (I) * 512 + lane * 8);
#define LOADF(P, BB) do { APPLY16B(LDF1, P, BB) __builtin_amdgcn_sched_barrier(0); } while (0)
#define LOADB(P, BB) do { APPLY16B(LDB1, P, BB) __builtin_amdgcn_sched_barrier(0); } while (0)

#define WAITG(RD, K, NS) do {                                                 \
        const int tgt_ = min(16 * (K) + 15, (NS) - 1);                        \
        for (;;) {                                                            \
            int r0_ = __hip_atomic_load(&RD[0], __ATOMIC_RELAXED, __HIP_MEMORY_SCOPE_WORKGROUP); \
            int r1_ = __hip_atomic_load(&RD[1], __ATOMIC_RELAXED, __HIP_MEMORY_SCOPE_WORKGROUP); \
            int r2_ = __hip_atomic_load(&RD[2], __ATOMIC_RELAXED, __HIP_MEMORY_SCOPE_WORKGROUP); \
            if (min(min(r0_, r1_), r2_) + 2 >= tgt_) break;                   \
            __builtin_amdgcn_s_sleep(2);                                      \
        }                                                                     \
        (void)__hip_atomic_load(&RD[0], __ATOMIC_ACQUIRE, __HIP_MEMORY_SCOPE_WORKGROUP); \
    } while (0)
#define PUBG(CN, K) do { if (lane == 0) __hip_atomic_store(&CN, 16 * (K) + 15, \
        __ATOMIC_RELEASE, __HIP_MEMORY_SCOPE_WORKGROUP); } while (0)

#define RESCALE() do {                                                        \
        float m_ = fmaxf(fmaxf(fmaxf(A0, A1), fmaxf(A2, A3)),                 \
                         fmaxf(fmaxf(A4, A5), fmaxf(A6, A7)));                \
        m_ = fmaxf(m_, A8);                                                   \
        DPPMAX_LADDER(m_);                                                    \
        m_ = lane_bcast(m_, 63);                                              \
        m_ = fmaxf(m_, 1e-30f);                                               \
        float inv_ = __builtin_amdgcn_rcpf(m_);                               \
        acc += __logf(m_);                                                    \
        A0 *= inv_; A1 *= inv_; A2 *= inv_; A3 *= inv_; A4 *= inv_;           \
        A5 *= inv_; A6 *= inv_; A7 *= inv_; A8 *= inv_;                       \
    } while (0)

    // fwd (ratio form): lane holds states 8l..8l+7, A8 = state 512 on lane 63
#define STEPF_CORE(HX, HY) do {                                               \
        const unsigned hx_ = (HX), hy_ = (HY);                                \
        const float u0_ = __uint_as_float(hx_ << 16);                         \
        const float u1_ = __uint_as_float(hx_ & 0xffff0000u);                 \
        const float u2_ = __uint_as_float(hy_ << 16);                         \
        const float u3_ = __uint_as_float(hy_ & 0xffff0000u);                 \
        const float pA7_ = dpp_shr1z(A7);                                     \
        A8 = A8 + A7;                                                         \
        A7 = u3_ * fmaf(aF3, A5, A7 + A6);                                    \
        A6 = A6 + A5;                                                         \
        A5 = u2_ * fmaf(aF2, A3, A5 + A4);                                    \
        A4 = A4 + A3;                                                         \
        A3 = u1_ * fmaf(aF1, A1, A3 + A2);                                    \
        A2 = A2 + A1;                                                         \
        A1 = u0_ * fmaf(aF0, pA7_, A1 + A0);                                  \
        A0 = A0 + pA7_;                                                       \
    } while (0)
    // bwd (ratio form): lane holds states 8l+1..8l+8, A8 = state 0 on lane 0
#define STEPB_CORE(HX, HY) do {                                               \
        const unsigned hx_ = (HX), hy_ = (HY);                                \
        const float u0_ = __uint_as_float(hx_ << 16);                         \
        const float u1_ = __uint_as_float(hx_ & 0xffff0000u);                 \
        const float u2_ = __uint_as_float(hy_ << 16);                         \
        const float u3_ = __uint_as_float(hy_ & 0xffff0000u);                 \
        const float nC0_ = dpp_shl1z(A0);                                     \
        A8 = A8 + A0;                                                         \
        A0 = u0_ * fmaf(aB0, A2, A0 + A1);                                    \
        A1 = A1 + A2;                                                         \
        A2 = u1_ * fmaf(aB1, A4, A2 + A3);                                    \
        A3 = A3 + A4;                                                         \
        A4 = u2_ * fmaf(aB2, A6, A4 + A5);                                    \
        A5 = A5 + A6;                                                         \
        A6 = u3_ * fmaf(aB3, nC0_, A6 + A7);                                  \
        A7 = A7 + nC0_;                                                       \
    } while (0)

#define SF(P, I)  STEPF_CORE(P##_##I.x, P##_##I.y);
#define SB(P, I)  STEPB_CORE(P##_##I.x, P##_##I.y);
#define SFG(P, I, SBASE) if ((SBASE) + (I) < NF) { SF(P, I) }
#define SBG(P, I, SBASE) if ((SBASE) + (I) < NB) { SB(P, I) }

#define DOF16(P) do {                                                         \
        SF(P,0) SF(P,1) SF(P,2) SF(P,3) SF(P,4) SF(P,5) SF(P,6) SF(P,7)       \
        RESCALE();                                                            \
        SF(P,8) SF(P,9) SF(P,10) SF(P,11) SF(P,12) SF(P,13) SF(P,14) SF(P,15) \
        RESCALE();                                                            \
    } while (0)
#define DOFPART(P, SBASE) do {                                                \
        SFG(P,0,SBASE) SFG(P,1,SBASE) SFG(P,2,SBASE) SFG(P,3,SBASE)           \
        SFG(P,4,SBASE) SFG(P,5,SBASE) SFG(P,6,SBASE) SFG(P,7,SBASE)           \
        RESCALE();                                                            \
        SFG(P,8,SBASE) SFG(P,9,SBASE) SFG(P,10,SBASE) SFG(P,11,SBASE)         \
        SFG(P,12,SBASE) SFG(P,13,SBASE) SFG(P,14,SBASE) SFG(P,15,SBASE)       \
        RESCALE();                                                            \
    } while (0)
#define DOB16(P) do {                                                         \
        SB(P,0) SB(P,1) SB(P,2) SB(P,3) SB(P,4) SB(P,5) SB(P,6) SB(P,7)       \
        RESCALE();                                                            \
        SB(P,8) SB(P,9) SB(P,10) SB(P,11) SB(P,12) SB(P,13) SB(P,14) SB(P,15) \
        RESCALE();                                                            \
    } while (0)
#define DOBPART(P, SBASE) do {                                                \
        SBG(P,0,SBASE) SBG(P,1,SBASE) SBG(P,2,SBASE) SBG(P,3,SBASE)           \
        SBG(P,4,SBASE) SBG(P,5,SBASE) SBG(P,6,SBASE) SBG(P,7,SBASE)           \
        RESCALE();                                                            \
        SBG(P,8,SBASE) SBG(P,9,SBASE) SBG(P,10,SBASE) SBG(P,11,SBASE)         \
        SBG(P,12,SBASE) SBG(P,13,SBASE) SBG(P,14,SBASE) SBG(P,15,SBASE)       \
        RESCALE();                                                            \
    } while (0)

    if (wv >= 2) {
        // ===================== PRODUCERS =====================
        const bool isF = (wv < 5);
        const int  pix = isF ? (wv - 2) : (wv - 5);
        unsigned short* ring = isF ? ringF : ringB;
        int* readyp = isF ? (readyF + pix) : (readyB + pix);
        int* consp  = isF ? &consF : &consB;
        const int N = isF ? NF : NB;
        float* stg = stage[wv - 2];
        float sls_loc = 0.f, slog_loc = 0.f;
        int slot = pix;                         // = sp % RING (stride 3, 3|RING)

        f32x4 pA0, pA1, pB0, pB1, pC0, pC1, pD0, pD1;

#define PISSUE(R0, R1, SP) do { if ((SP) < N) {                               \
        const int t_ = isF ? (1 + (SP)) : (a_len - 2 - (SP));                 \
        const f32x4* p_ = (const f32x4*)(acts + ((size_t)t_ * B + b) * V);    \
        R0 = __builtin_nontemporal_load(p_ + lane);                           \
        R1 = __builtin_nontemporal_load(p_ + lane + 64);                      \
        __builtin_amdgcn_sched_barrier(0);                                    \
    } } while (0)

#define PPROC(R0, R1, SP) do { if ((SP) < N) {                                \
        PINV(R0.x); PINV(R0.y); PINV(R0.z); PINV(R0.w);                       \
        PINV(R1.x); PINV(R1.y); PINV(R1.z); PINV(R1.w);                       \
        f32x4 ex0_, ex1_;                                                     \
        ex0_.x=__expf(R0.x); ex0_.y=__expf(R0.y); ex0_.z=__expf(R0.z); ex0_.w=__expf(R0.w); \
        ex1_.x=__expf(R1.x); ex1_.y=__expf(R1.y); ex1_.z=__expf(R1.z); ex1_.w=__expf(R1.w); \
        float sm_ = ex0_.x+ex0_.y+ex0_.z+ex0_.w + ex1_.x+ex1_.y+ex1_.z+ex1_.w;\
        DPPADD_LADDER(sm_);                                                   \
        sls_loc  += __logf(lane_bcast(sm_, 63));                              \
        slog_loc += lane_bcast(R0.x, 0);                                      \
        const float rub_ = __builtin_amdgcn_rcpf(lane_bcast(ex0_.x, 0));      \
        ((f32x4*)stg)[lane]      = ex0_;   /* floats 4l..4l+3   */            \
        ((f32x4*)stg)[lane + 64] = ex1_;   /* floats 256+4l..   */            \
        while (__hip_atomic_load(consp, __ATOMIC_ACQUIRE,                     \
                                 __HIP_MEMORY_SCOPE_WORKGROUP) < (SP) - RING) \
            __builtin_amdgcn_s_sleep(2);                                      \
        float q0_ = (li0 + 0 < lab_len) ? stg[e0] * rub_ : 1.f;               \
        float q1_ = (li0 + 1 < lab_len) ? stg[e1] * rub_ : 1.f;               \
        float q2_ = (li0 + 2 < lab_len) ? stg[e2] * rub_ : 1.f;               \
        float q3_ = (li0 + 3 < lab_len) ? stg[e3] * rub_ : 1.f;               \
        uint2 pk_;                                                            \
        pk_.x = (unsigned)f2bf(q0_) | ((unsigned)f2bf(q1_) << 16);            \
        pk_.y = (unsigned)f2bf(q2_) | ((unsigned)f2bf(q3_) << 16);            \
        *(uint2*)((char*)ring + slot * 512 + lane * 8) = pk_;                 \
        if (lane == 0)                                                        \
            __hip_atomic_store(readyp, (SP), __ATOMIC_RELEASE,                \
                               __HIP_MEMORY_SCOPE_WORKGROUP);                 \
        slot += 3; if (slot >= RING) slot -= RING;                            \
    } } while (0)

        int sp = pix;
        PISSUE(pA0, pA1, sp);     PISSUE(pB0, pB1, sp + 3);
        PISSUE(pC0, pC1, sp + 6); PISSUE(pD0, pD1, sp + 9);
        for (; sp < N; sp += 12) {
            PPROC(pA0, pA1, sp);      PISSUE(pA0, pA1, sp + 12);
            PPROC(pB0, pB1, sp + 3);  PISSUE(pB0, pB1, sp + 15);
            PPROC(pC0, pC1, sp + 6);  PISSUE(pC0, pC1, sp + 18);
            PPROC(pD0, pD1, sp + 9);  PISSUE(pD0, pD1, sp + 21);
        }
        if (lane == 0) { parts_sls[wv] = sls_loc; parts_slog[wv] = slog_loc; }
#undef PISSUE
#undef PPROC
    } else if (wv == 0) {
        // ===================== FWD SCAN =====================
        {   // row t=0: lse0, A0=exp(x_blank), A1=exp(x_label0)
            const f32x4* p0 = (const f32x4*)(acts + (size_t)b * V);
            f32x4 r0 = p0[lane], r1 = p0[lane + 64];
            f32x4 e0v, e1v;
            e0v.x=__expf(r0.x); e0v.y=__expf(r0.y); e0v.z=__expf(r0.z); e0v.w=__expf(r0.w);
            e1v.x=__expf(r1.x); e1v.y=__expf(r1.y); e1v.z=__expf(r1.z); e1v.w=__expf(r1.w);
            float sm = e0v.x+e0v.y+e0v.z+e0v.w + e1v.x+e1v.y+e1v.z+e1v.w;
            DPPADD_LADDER(sm);
            float lse0 = __logf(lane_bcast(sm, 63));
            float ub0  = lane_bcast(e0v.x, 0);
            int   k    = (lab_len > 0) ? labels[min(off, B * L - 1)] : 0;
            float vloc = (k < 256) ? sel4(e0v, k & 3) : sel4(e1v, k & 3);
            float A1v  = lane_bcast(vloc, (k < 256) ? (k >> 2) : ((k - 256) >> 2));
            if (lane == 0) {
                A0 = ub0; A1 = A1v;
                parts_sls[0] = lse0; parts_slog[0] = 0.f;
            }
        }
        if (NF >= 1) {
            const int nc = (NF + 15) >> 4, nfull = NF >> 4;
            if (0 < nc) { WAITG(readyF, 0, NF); LOADF(a, 0); }
            if (1 < nc) { WAITG(readyF, 1, NF); LOADF(b, 8192); }
            if (2 < nc) { WAITG(readyF, 2, NF); LOADF(c, 16384); }
            int cc = 0;
            for (; cc + 3 <= nfull; cc += 3) {
                PINCH(a); PUBG(consF, cc);     DOF16(a);
                if (cc + 3 < nc) { WAITG(readyF, cc + 3, NF); LOADF(a, 0); }
                PINCH(b); PUBG(consF, cc + 1); DOF16(b);
                if (cc + 4 < nc) { WAITG(readyF, cc + 4, NF); LOADF(b, 8192); }
                PINCH(c); PUBG(consF, cc + 2); DOF16(c);
                if (cc + 5 < nc) { WAITG(readyF, cc + 5, NF); LOADF(c, 16384); }
            }
            const int rem = nfull - cc;
            if (rem == 0) {
                if (nc > nfull) { PINCH(a); PUBG(consF, cc); DOFPART(a, 16 * cc); }
            } else if (rem == 1) {
                PINCH(a); PUBG(consF, cc); DOF16(a);
                if (nc > nfull) { PINCH(b); PUBG(consF, cc + 1); DOFPART(b, 16 * (cc + 1)); }
            } else {
                PINCH(a); PUBG(consF, cc); DOF16(a);
                PINCH(b); PUBG(consF, cc + 1); DOF16(b);
                if (nc > nfull) { PINCH(c); PUBG(consF, cc + 2); DOFPART(c, 16 * (cc + 2)); }
            }
        }
    } else {
        // ===================== BWD SCAN (wv == 1) =====================
        {   // row t=a_len-1: lse_last, ubl, ue
            const f32x4* p1 = (const f32x4*)(acts + ((size_t)(a_len - 1) * B + b) * V);
            f32x4 r0 = p1[lane], r1 = p1[lane + 64];
            f32x4 e0v, e1v;
            e0v.x=__expf(r0.x); e0v.y=__expf(r0.y); e0v.z=__expf(r0.z); e0v.w=__expf(r0.w);
            e1v.x=__expf(r1.x); e1v.y=__expf(r1.y); e1v.z=__expf(r1.z); e1v.w=__expf(r1.w);
            float sm = e0v.x+e0v.y+e0v.z+e0v.w + e1v.x+e1v.y+e1v.z+e1v.w;
            DPPADD_LADDER(sm);
            float lsel = __logf(lane_bcast(sm, 63));
            float ubl  = lane_bcast(e0v.x, 0);
            float ue   = 0.f;
            if (lab_len > 0) {
                int k = labels[min(off + lab_len - 1, B * L - 1)];
                float vloc = (k < 256) ? sel4(e0v, k & 3) : sel4(e1v, k & 3);
                ue = lane_bcast(vloc, (k < 256) ? (k >> 2) : ((k - 256) >> 2));
            }
            if (lane == 0) {
                parts_sls[1]  = (a_len > 1) ? lsel : 0.f;
                parts_slog[1] = 0.f;
            }
            const int send = 2 * lab_len;
            int s0 = 8 * lane + 1;                  // states s0..s0+7
            A0 = (s0 + 0 == send) ? ubl : ((s0 + 0 == send - 1) ? ue : 0.f);
            A1 = (s0 + 1 == send) ? ubl : ((s0 + 1 == send - 1) ? ue : 0.f);
            A2 = (s0 + 2 == send) ? ubl : ((s0 + 2 == send - 1) ? ue : 0.f);
            A3 = (s0 + 3 == send) ? ubl : ((s0 + 3 == send - 1) ? ue : 0.f);
            A4 = (s0 + 4 == send) ? ubl : ((s0 + 4 == send - 1) ? ue : 0.f);
            A5 = (s0 + 5 == send) ? ubl : ((s0 + 5 == send - 1) ? ue : 0.f);
            A6 = (s0 + 6 == send) ? ubl : ((s0 + 6 == send - 1) ? ue : 0.f);
            A7 = (s0 + 7 == send) ? ubl : ((s0 + 7 == send - 1) ? ue : 0.f);
            A8 = (send == 0) ? ubl : 0.f;           // state 0 (lane 0's only used)
        }
        if (NB >= 1) {
            const int nc = (NB + 15) >> 4, nfull = NB >> 4;
            if (0 < nc) { WAITG(readyB, 0, NB); LOADB(a, 0); }
            if (1 < nc) { WAITG(readyB, 1, NB); LOADB(b, 8192); }
            if (2 < nc) { WAITG(readyB, 2, NB); LOADB(c, 16384); }
            int cc = 0;
            for (; cc + 3 <= nfull; cc += 3) {
                PINCH(a); PUBG(consB, cc);     DOB16(a);
                if (cc + 3 < nc) { WAITG(readyB, cc + 3, NB); LOADB(a, 0); }
                PINCH(b); PUBG(consB, cc + 1); DOB16(b);
                if (cc + 4 < nc) { WAITG(readyB, cc + 4, NB); LOADB(b, 8192); }
                PINCH(c); PUBG(consB, cc + 2); DOB16(c);
                if (cc + 5 < nc) { WAITG(readyB, cc + 5, NB); LOADB(c, 16384); }
            }
            const int rem = nfull - cc;
            if (rem == 0) {
                if (nc > nfull) { PINCH(a); PUBG(consB, cc); DOBPART(a, 16 * cc); }
            } else if (rem == 1) {
                PINCH(a); PUBG(consB, cc); DOB16(a);
                if (nc > nfull) { PINCH(b); PUBG(consB, cc + 1); DOBPART(b, 16 * (cc + 1)); }
            } else {
                PINCH(a); PUBG(consB, cc); DOB16(a);
                PINCH(b); PUBG(consB, cc + 1); DOB16(b);
                if (nc > nfull) { PINCH(c); PUBG(consB, cc + 2); DOBPART(c, 16 * (cc + 2)); }
            }
        }
        {   // bracket W(s) = B(s) + B(s+1) + allow(s+2)*B(s+2)
            float nC0 = dpp_shl1z(A0);
            float w1 = fmaf(aB0, A2, A0 + A1);      // s = 8l+1
            float w2 = A1 + A2;                     // s = 8l+2
            float w3 = fmaf(aB1, A4, A2 + A3);      // s = 8l+3
            float w4 = A3 + A4;                     // s = 8l+4
            float w5 = fmaf(aB2, A6, A4 + A5);      // s = 8l+5
            float w6 = A5 + A6;                     // s = 8l+6
            float w7 = fmaf(aB3, nC0, A6 + A7);     // s = 8l+7
            float w8 = A7 + nC0;                    // s = 8l+8
            int sB = 8 * lane + 1;
            sbr[sB + 0] = w1; sbr[sB + 1] = w2; sbr[sB + 2] = w3; sbr[sB + 3] = w4;
            sbr[sB + 4] = w5; sbr[sB + 5] = w6; sbr[sB + 6] = w7; sbr[sB + 7] = w8;
            if (lane == 0) sbr[0] = A8 + A0;        // W(0) = B(0) + B(1)
            if (lane == 0) s_accb = acc;
        }
    }
    __syncthreads();
    if (wv == 0) {
        // LOG-space junction (linear dot of the two independently-rescaled
        // sides underflows fp32)
        float sls = 0.f, slog = 0.f;
#pragma unroll
        for (int i = 0; i < 8; ++i) { sls += parts_sls[i]; slog += parts_slog[i]; }
        int s0 = 8 * lane;
        float p0 = __logf(fmaxf(A0, 1e-37f)) + __logf(fmaxf(sbr[s0 + 0], 1e-37f));
        float p1 = __logf(fmaxf(A1, 1e-37f)) + __logf(fmaxf(sbr[s0 + 1], 1e-37f));
        float p2 = __logf(fmaxf(A2, 1e-37f)) + __logf(fmaxf(sbr[s0 + 2], 1e-37f));
        float p3 = __logf(fmaxf(A3, 1e-37f)) + __logf(fmaxf(sbr[s0 + 3], 1e-37f));
        float p4 = __logf(fmaxf(A4, 1e-37f)) + __logf(fmaxf(sbr[s0 + 4], 1e-37f));
        float p5 = __logf(fmaxf(A5, 1e-37f)) + __logf(fmaxf(sbr[s0 + 5], 1e-37f));
        float p6 = __logf(fmaxf(A6, 1e-37f)) + __logf(fmaxf(sbr[s0 + 6], 1e-37f));
        float p7 = __logf(fmaxf(A7, 1e-37f)) + __logf(fmaxf(sbr[s0 + 7], 1e-37f));
        float p8 = -3.0e38f;
        if (lane == 63) p8 = __logf(fmaxf(A8, 1e-37f)) + __logf(fmaxf(sbr[512], 1e-37f));
        float pmax = fmaxf(fmaxf(fmaxf(p0, p1), fmaxf(p2, p3)),
                           fmaxf(fmaxf(p4, p5), fmaxf(p6, p7)));
        pmax = fmaxf(pmax, p8);
        DPPMAX_LADDER(pmax);
        pmax = lane_bcast(pmax, 63);
        float dot = __expf(p0 - pmax) + __expf(p1 - pmax) + __expf(p2 - pmax)
                  + __expf(p3 - pmax) + __expf(p4 - pmax) + __expf(p5 - pmax)
                  + __expf(p6 - pmax) + __expf(p7 - pmax);
        if (lane == 63) dot += __expf(p8 - pmax);
        DPPADD_LADDER(dot);
        dot = lane_bcast(dot, 63);
        if (lane == 0) {
            float loss = sls - slog - acc - s_accb - (pmax + __logf(dot));
            atomicAdd(out, loss);
        }
    }
#undef PINV
#undef APPLY16
#undef APPLY16B
#undef PIN1
#undef PINCH
#undef LDF1
#undef LDB1
#undef LOADF
#undef LOADB
#undef WAITG
#undef PUBG
#undef RESCALE
#undef STEPF_CORE
#undef STEPB_CORE
#undef SF
#undef SB
#undef SFG
#undef SBG
#undef DOF16
#undef DOFPART
#undef DOB16
#undef DOBPART
}

extern "C" void kernel_launch(void* const* d_in, const int* in_sizes, int n_in,
                              void* d_out, int out_size, void* d_ws, size_t ws_size,
                              hipStream_t stream) {
    const float* acts       = (const float*)d_in[0];
    const int*   labels     = (const int*)d_in[1];
    const int*   act_lens   = (const int*)d_in[2];
    const int*   label_lens = (const int*)d_in[3];
    float*       out        = (float*)d_out;

    hipMemsetAsync(d_out, 0, sizeof(float), stream);
    fused_kernel<<<B, 512, 0, stream>>>(acts, labels, act_lens, label_lens, out);
}